// Round 1
// baseline (217.122 us; speedup 1.0000x reference)
//
#include <hip/hip_runtime.h>
#include <stdint.h>

#define D 2048
#define R 64
#define M_TOTAL 8192

typedef float f32x4 __attribute__((ext_vector_type(4)));
typedef __bf16 bf16x8 __attribute__((ext_vector_type(8)));
typedef unsigned short u16x8 __attribute__((ext_vector_type(8)));
typedef unsigned short u16x4 __attribute__((ext_vector_type(4)));

__device__ __forceinline__ unsigned short f2bf(float f) {
  unsigned u = __builtin_bit_cast(unsigned, f);
  u += 0x7FFFu + ((u >> 16) & 1u);
  return (unsigned short)(u >> 16);
}

__device__ __forceinline__ void gload_lds16(const void* g, void* l) {
  __builtin_amdgcn_global_load_lds(
      (const __attribute__((address_space(1))) void*)g,
      (__attribute__((address_space(3))) void*)l, 16, 0, 0);
}

// ---------------- prep: f32 -> bf16 conversions (x, W1, W2) ----------------
__global__ void conv_kernel(const float* __restrict__ x, const float* __restrict__ w1,
                            const float* __restrict__ w2, unsigned short* __restrict__ xbf,
                            unsigned short* __restrict__ w1bf, unsigned short* __restrict__ w2bf) {
  const int NX4 = (M_TOTAL * D) / 4;  // 4,194,304 float4 groups
  const int NW4 = (R * D) / 4;        // 32,768
  int stride = gridDim.x * blockDim.x;
  for (int i = blockIdx.x * blockDim.x + threadIdx.x; i < NX4 + 2 * NW4; i += stride) {
    const float4* src; unsigned short* dst; int j;
    if (i < NX4)            { src = (const float4*)x;  dst = xbf;  j = i; }
    else if (i < NX4 + NW4) { src = (const float4*)w1; dst = w1bf; j = i - NX4; }
    else                    { src = (const float4*)w2; dst = w2bf; j = i - NX4 - NW4; }
    float4 v = src[j];
    u16x4 o = { f2bf(v.x), f2bf(v.y), f2bf(v.z), f2bf(v.w) };
    *(u16x4*)(dst + (size_t)j * 4) = o;
  }
}

// ---------------- prep: St[n][k] = bf16(A[k][n]+B[k][n]+C[k][n]) ----------------
__global__ void sumt_kernel(const float* __restrict__ A, const float* __restrict__ B,
                            const float* __restrict__ C, unsigned short* __restrict__ st) {
  __shared__ unsigned short lds[64][68];
  int t = threadIdx.x;
  int tk = blockIdx.x >> 5, tn = blockIdx.x & 31;
  int k0 = tk * 64, n0 = tn * 64;
#pragma unroll
  for (int q = 0; q < 4; ++q) {
    int row = q * 16 + (t >> 4);
    int col = (t & 15) * 4;
    size_t off = (size_t)(k0 + row) * D + n0 + col;
    float4 a = *(const float4*)(A + off);
    float4 b = *(const float4*)(B + off);
    float4 c = *(const float4*)(C + off);
    u16x4 o = { f2bf(a.x + b.x + c.x), f2bf(a.y + b.y + c.y),
                f2bf(a.z + b.z + c.z), f2bf(a.w + b.w + c.w) };
    *(u16x4*)(&lds[row][col]) = o;
  }
  __syncthreads();
  int n = t >> 2, kc = (t & 3) * 16;
  u16x8 v0, v1;
#pragma unroll
  for (int jj = 0; jj < 8; ++jj) v0[jj] = lds[kc + jj][n];
#pragma unroll
  for (int jj = 0; jj < 8; ++jj) v1[jj] = lds[kc + 8 + jj][n];
  size_t ooff = (size_t)(n0 + n) * D + k0 + kc;
  *(u16x8*)(st + ooff) = v0;
  *(u16x8*)(st + ooff + 8) = v1;
}

// ---------------- h = bf16(gelu(x @ W1^T + b1)), (8192 x 64) ----------------
__global__ __launch_bounds__(256) void h_kernel(const unsigned short* __restrict__ xbf,
                                                const unsigned short* __restrict__ w1bf,
                                                const float* __restrict__ b1,
                                                unsigned short* __restrict__ hbf) {
  __shared__ unsigned short sX[2048];
  __shared__ unsigned short sW[2048];
  int t = threadIdx.x;
  int w = t >> 6, l = t & 63;
  int lm = l & 15, lk = l >> 4;
  int m0 = blockIdx.x * 64;
  f32x4 acc[4] = {};

  int row = t & 63, khalf = t >> 6;
  const unsigned short* srcX = xbf + (size_t)(m0 + row) * D + khalf * 8;
  const unsigned short* srcW = w1bf + (size_t)row * D + khalf * 8;
  unsigned short* dX = sX + w * 512;  // wave-uniform LDS base (HW adds lane*16B)
  unsigned short* dW = sW + w * 512;
  const unsigned short* pX = sX + lk * 512 + (w * 16 + lm) * 8;
  const unsigned short* pW = sW + lk * 512 + lm * 8;

#pragma unroll 1
  for (int k0 = 0; k0 < D; k0 += 32) {
    __syncthreads();
    gload_lds16(srcX + k0, dX);
    gload_lds16(srcW + k0, dW);
    __syncthreads();
    bf16x8 a = __builtin_bit_cast(bf16x8, *(const u16x8*)pX);
#pragma unroll
    for (int j = 0; j < 4; ++j) {
      bf16x8 b = __builtin_bit_cast(bf16x8, *(const u16x8*)(pW + j * 128));
      acc[j] = __builtin_amdgcn_mfma_f32_16x16x32_bf16(a, b, acc[j], 0, 0, 0);
    }
  }

  int m_base = m0 + w * 16 + lk * 4;
#pragma unroll
  for (int j = 0; j < 4; ++j) {
    int n = j * 16 + lm;
    float bv = b1[n];
#pragma unroll
    for (int r = 0; r < 4; ++r) {
      float v = acc[j][r] + bv;
      float g = 0.5f * v * (1.0f + erff(v * 0.70710678118654752f));
      hbf[(size_t)(m_base + r) * R + n] = f2bf(g);
    }
  }
}

// ---------------- main: out = (x @ S) * dt + Dp, fused epilogue ----------------
__global__ __launch_bounds__(256) void gemm_kernel(
    const unsigned short* __restrict__ xbf, const unsigned short* __restrict__ st,
    const unsigned short* __restrict__ hbf, const unsigned short* __restrict__ w2bf,
    const float* __restrict__ b2, const float* __restrict__ dp,
    float* __restrict__ out) {
  __shared__ unsigned short sA[4096];  // [khalf][128 rows][8] bf16, 8KB
  __shared__ unsigned short sB[4096];
  int t = threadIdx.x;
  int w = t >> 6, l = t & 63;
  int lm = l & 15, lk = l >> 4;
  int wr = w >> 1, wc = w & 1;
  int bid = blockIdx.x;
  int wg = (bid & 7) * 128 + (bid >> 3);  // XCD-aware bijective swizzle (1024 wgs)
  int mb = wg >> 4, nb = wg & 15;
  int m0 = mb * 128, n0 = nb * 128;

  f32x4 acc[4][4] = {};

  // staging: issue q in {0,1}; chunk c=q*256+t; khalf=c>>7, row=c&127
  int row = t & 127;
  int kh0 = t >> 7;  // 0..1
  const unsigned short* srcA0 = xbf + (size_t)(m0 + row) * D + kh0 * 8;
  const unsigned short* srcA1 = xbf + (size_t)(m0 + row) * D + (kh0 + 2) * 8;
  const unsigned short* srcB0 = st + (size_t)(n0 + row) * D + kh0 * 8;
  const unsigned short* srcB1 = st + (size_t)(n0 + row) * D + (kh0 + 2) * 8;
  unsigned short* dA0 = sA + w * 512;         // wave-uniform bases
  unsigned short* dA1 = sA + 2048 + w * 512;
  unsigned short* dB0 = sB + w * 512;
  unsigned short* dB1 = sB + 2048 + w * 512;

  const unsigned short* pA = sA + lk * 1024 + (wr * 64 + lm) * 8;
  const unsigned short* pB = sB + lk * 1024 + (wc * 64 + lm) * 8;

#pragma unroll 1
  for (int k0 = 0; k0 < D; k0 += 32) {
    __syncthreads();
    gload_lds16(srcA0 + k0, dA0);
    gload_lds16(srcA1 + k0, dA1);
    gload_lds16(srcB0 + k0, dB0);
    gload_lds16(srcB1 + k0, dB1);
    __syncthreads();
    bf16x8 a[4], b[4];
#pragma unroll
    for (int i = 0; i < 4; ++i)
      a[i] = __builtin_bit_cast(bf16x8, *(const u16x8*)(pA + i * 128));
#pragma unroll
    for (int j = 0; j < 4; ++j)
      b[j] = __builtin_bit_cast(bf16x8, *(const u16x8*)(pB + j * 128));
#pragma unroll
    for (int i = 0; i < 4; ++i)
#pragma unroll
      for (int j = 0; j < 4; ++j)
        acc[i][j] = __builtin_amdgcn_mfma_f32_16x16x32_bf16(a[i], b[j], acc[i][j], 0, 0, 0);
  }

  // epilogue: dt = h @ W2^T + b2 (rank-64, 2 MFMA per fragment), out = acc*dt + Dp
  bf16x8 ha[4][2];
#pragma unroll
  for (int i = 0; i < 4; ++i) {
    int hrow = m0 + wr * 64 + i * 16 + lm;
    const u16x8* hp = (const u16x8*)(hbf + (size_t)hrow * R + lk * 8);
    ha[i][0] = __builtin_bit_cast(bf16x8, hp[0]);
    ha[i][1] = __builtin_bit_cast(bf16x8, hp[4]);  // +32 bf16
  }
  bf16x8 wb[4][2];
  float b2v[4], dpv[4];
#pragma unroll
  for (int j = 0; j < 4; ++j) {
    int n = n0 + wc * 64 + j * 16 + lm;
    const u16x8* wp = (const u16x8*)(w2bf + (size_t)n * R + lk * 8);
    wb[j][0] = __builtin_bit_cast(bf16x8, wp[0]);
    wb[j][1] = __builtin_bit_cast(bf16x8, wp[4]);
    b2v[j] = b2[n];
    dpv[j] = dp[n];
  }
#pragma unroll
  for (int i = 0; i < 4; ++i) {
    int m_base = m0 + wr * 64 + i * 16 + lk * 4;
#pragma unroll
    for (int j = 0; j < 4; ++j) {
      f32x4 dt = {};
      dt = __builtin_amdgcn_mfma_f32_16x16x32_bf16(ha[i][0], wb[j][0], dt, 0, 0, 0);
      dt = __builtin_amdgcn_mfma_f32_16x16x32_bf16(ha[i][1], wb[j][1], dt, 0, 0, 0);
      int n = n0 + wc * 64 + j * 16 + lm;
#pragma unroll
      for (int r = 0; r < 4; ++r) {
        float val = acc[i][j][r] * (dt[r] + b2v[j]) + dpv[j];
        out[(size_t)(m_base + r) * D + n] = val;
      }
    }
  }
}

extern "C" void kernel_launch(void* const* d_in, const int* in_sizes, int n_in,
                              void* d_out, int out_size, void* d_ws, size_t ws_size,
                              hipStream_t stream) {
  const float* x  = (const float*)d_in[0];
  const float* A  = (const float*)d_in[1];
  const float* B  = (const float*)d_in[2];
  const float* C  = (const float*)d_in[3];
  const float* Dp = (const float*)d_in[4];
  const float* W1 = (const float*)d_in[5];
  const float* b1 = (const float*)d_in[6];
  const float* W2 = (const float*)d_in[7];
  const float* b2 = (const float*)d_in[8];
  float* out = (float*)d_out;

  uint8_t* ws = (uint8_t*)d_ws;
  unsigned short* xbf  = (unsigned short*)ws;                              // 32 MB
  unsigned short* st   = (unsigned short*)(ws + (32u << 20));              // 8 MB
  unsigned short* w1bf = (unsigned short*)(ws + (40u << 20));              // 256 KB
  unsigned short* w2bf = (unsigned short*)(ws + (40u << 20) + (256u << 10)); // 256 KB
  unsigned short* hbf  = (unsigned short*)(ws + (41u << 20));              // 1 MB

  conv_kernel<<<2048, 256, 0, stream>>>(x, W1, W2, xbf, w1bf, w2bf);
  sumt_kernel<<<1024, 256, 0, stream>>>(A, B, C, st);
  h_kernel<<<128, 256, 0, stream>>>(xbf, w1bf, b1, hbf);
  gemm_kernel<<<1024, 256, 0, stream>>>(xbf, st, hbf, w2bf, b2, Dp, out);
}

// Round 2
// 136.305 us; speedup vs baseline: 1.5929x; 1.5929x over previous
//
#include <hip/hip_runtime.h>
#include <stdint.h>

#define D 2048
#define R 64
#define M_TOTAL 8192

typedef float f32x4 __attribute__((ext_vector_type(4)));
typedef __bf16 bf16x8 __attribute__((ext_vector_type(8)));
typedef unsigned short u16x8 __attribute__((ext_vector_type(8)));
typedef unsigned short u16x4 __attribute__((ext_vector_type(4)));

__device__ __forceinline__ unsigned short f2bf(float f) {
  unsigned u = __builtin_bit_cast(unsigned, f);
  u += 0x7FFFu + ((u >> 16) & 1u);
  return (unsigned short)(u >> 16);
}

__device__ __forceinline__ void gload_lds16(const void* g, void* l) {
  __builtin_amdgcn_global_load_lds(
      (const __attribute__((address_space(1))) void*)g,
      (__attribute__((address_space(3))) void*)l, 16, 0, 0);
}

// ---------------- prep: f32 -> bf16 conversions (x, W1, W2) ----------------
__global__ void conv_kernel(const float* __restrict__ x, const float* __restrict__ w1,
                            const float* __restrict__ w2, unsigned short* __restrict__ xbf,
                            unsigned short* __restrict__ w1bf, unsigned short* __restrict__ w2bf) {
  const int NX4 = (M_TOTAL * D) / 4;
  const int NW4 = (R * D) / 4;
  int stride = gridDim.x * blockDim.x;
  for (int i = blockIdx.x * blockDim.x + threadIdx.x; i < NX4 + 2 * NW4; i += stride) {
    const float4* src; unsigned short* dst; int j;
    if (i < NX4)            { src = (const float4*)x;  dst = xbf;  j = i; }
    else if (i < NX4 + NW4) { src = (const float4*)w1; dst = w1bf; j = i - NX4; }
    else                    { src = (const float4*)w2; dst = w2bf; j = i - NX4 - NW4; }
    float4 v = src[j];
    u16x4 o = { f2bf(v.x), f2bf(v.y), f2bf(v.z), f2bf(v.w) };
    *(u16x4*)(dst + (size_t)j * 4) = o;
  }
}

// ---------------- prep: St[n][k] = bf16(A[k][n]+B[k][n]+C[k][n]) ----------------
__global__ void sumt_kernel(const float* __restrict__ A, const float* __restrict__ B,
                            const float* __restrict__ C, unsigned short* __restrict__ st) {
  __shared__ unsigned short lds[64][68];
  int t = threadIdx.x;
  int tk = blockIdx.x >> 5, tn = blockIdx.x & 31;
  int k0 = tk * 64, n0 = tn * 64;
#pragma unroll
  for (int q = 0; q < 4; ++q) {
    int row = q * 16 + (t >> 4);
    int col = (t & 15) * 4;
    size_t off = (size_t)(k0 + row) * D + n0 + col;
    float4 a = *(const float4*)(A + off);
    float4 b = *(const float4*)(B + off);
    float4 c = *(const float4*)(C + off);
    u16x4 o = { f2bf(a.x + b.x + c.x), f2bf(a.y + b.y + c.y),
                f2bf(a.z + b.z + c.z), f2bf(a.w + b.w + c.w) };
    *(u16x4*)(&lds[row][col]) = o;
  }
  __syncthreads();
  int n = t >> 2, kc = (t & 3) * 16;
  u16x8 v0, v1;
#pragma unroll
  for (int jj = 0; jj < 8; ++jj) v0[jj] = lds[kc + jj][n];
#pragma unroll
  for (int jj = 0; jj < 8; ++jj) v1[jj] = lds[kc + 8 + jj][n];
  size_t ooff = (size_t)(n0 + n) * D + k0 + kc;
  *(u16x8*)(st + ooff) = v0;
  *(u16x8*)(st + ooff + 8) = v1;
}

// ---------------- h = bf16(gelu(x @ W1^T + b1)), (8192 x 64) ----------------
__global__ __launch_bounds__(256) void h_kernel(const unsigned short* __restrict__ xbf,
                                                const unsigned short* __restrict__ w1bf,
                                                const float* __restrict__ b1,
                                                unsigned short* __restrict__ hbf) {
  __shared__ unsigned short sX[2048];
  __shared__ unsigned short sW[2048];
  int t = threadIdx.x;
  int w = t >> 6, l = t & 63;
  int lm = l & 15, lk = l >> 4;
  int m0 = blockIdx.x * 64;
  f32x4 acc[4] = {};

  int row = t & 63, khalf = t >> 6;
  const unsigned short* srcX = xbf + (size_t)(m0 + row) * D + khalf * 8;
  const unsigned short* srcW = w1bf + (size_t)row * D + khalf * 8;
  unsigned short* dX = sX + w * 512;
  unsigned short* dW = sW + w * 512;
  const unsigned short* pX = sX + lk * 512 + (w * 16 + lm) * 8;
  const unsigned short* pW = sW + lk * 512 + lm * 8;

#pragma unroll 1
  for (int k0 = 0; k0 < D; k0 += 32) {
    __syncthreads();
    gload_lds16(srcX + k0, dX);
    gload_lds16(srcW + k0, dW);
    __syncthreads();
    bf16x8 a = __builtin_bit_cast(bf16x8, *(const u16x8*)pX);
#pragma unroll
    for (int j = 0; j < 4; ++j) {
      bf16x8 b = __builtin_bit_cast(bf16x8, *(const u16x8*)(pW + j * 128));
      acc[j] = __builtin_amdgcn_mfma_f32_16x16x32_bf16(a, b, acc[j], 0, 0, 0);
    }
  }

  int m_base = m0 + w * 16 + lk * 4;
#pragma unroll
  for (int j = 0; j < 4; ++j) {
    int n = j * 16 + lm;
    float bv = b1[n];
#pragma unroll
    for (int r = 0; r < 4; ++r) {
      float v = acc[j][r] + bv;
      float g = 0.5f * v * (1.0f + erff(v * 0.70710678118654752f));
      hbf[(size_t)(m_base + r) * R + n] = f2bf(g);
    }
  }
}

// ---------------- main: out = (x @ S) * dt + Dp ----------------
// 256x256 tile, BK=32, 8 waves (2M x 4N), 4-deep LDS ring, counted vmcnt(4),
// raw s_barrier (never drain vmcnt to 0 in steady state), setprio around MFMA,
// XOR-swizzled LDS (both-sides: inverse-permuted global src + swizzled ds_read).
__global__ __launch_bounds__(512, 2) void gemm_kernel(
    const unsigned short* __restrict__ xbf, const unsigned short* __restrict__ st,
    const unsigned short* __restrict__ hbf, const unsigned short* __restrict__ w2bf,
    const float* __restrict__ b2, const float* __restrict__ dp,
    float* __restrict__ out) {
  __shared__ unsigned short sA[32768];  // 4 bufs x 256 rows x 32 k, 64 KB
  __shared__ unsigned short sB[32768];  // 64 KB
  const int tid = threadIdx.x;
  const int w = tid >> 6, l = tid & 63, lk = l >> 4, lm = l & 15;
  const int wm = w >> 2, wn = w & 3;
  int bid = blockIdx.x;
  int wg = (bid & 7) * 32 + (bid >> 3);  // bijective XCD swizzle (256 wgs)
  int mb = wg >> 3, nb = wg & 7;
  int m0 = mb * 256, n0 = nb * 256;

  // staging precompute: chunk c = q*512 + tid; row = c>>2; phys kslot kp = c&3
  // LDS granule (row, kp) receives logical k-granule kg = kp ^ ((row>>1)&3)
  const int r0 = tid >> 2;
  const int kg = (tid & 3) ^ ((tid >> 3) & 3);  // same for q=0 and q=1 (row +128)
  const unsigned short* gA0 = xbf + (size_t)(m0 + r0) * D + kg * 8;
  const unsigned short* gA1 = xbf + (size_t)(m0 + 128 + r0) * D + kg * 8;
  const unsigned short* gB0 = st + (size_t)(n0 + r0) * D + kg * 8;
  const unsigned short* gB1 = st + (size_t)(n0 + 128 + r0) * D + kg * 8;
  const int dst0 = w * 512;  // shorts; wave-uniform LDS base (HW adds lane*16B)

  // fragment-read precompute: read physical kslot = lk ^ ((row>>1)&3); for our
  // rows (base + lm) the XOR term is s = (lm>>1)&3, independent of frag index.
  const int s = (lm >> 1) & 3;
  const int aoff = (wm * 128 + lm) * 32 + ((lk ^ s) * 8);
  const int boff = (wn * 64 + lm) * 32 + ((lk ^ s) * 8);

  f32x4 acc[8][4] = {};

#define STAGE_A(kt) do { int o_ = ((kt) & 3) * 8192; int ko_ = (kt) * 32; \
    gload_lds16(gA0 + ko_, sA + o_ + dst0); \
    gload_lds16(gA1 + ko_, sA + o_ + 4096 + dst0); } while (0)
#define STAGE_B(kt) do { int o_ = ((kt) & 3) * 8192; int ko_ = (kt) * 32; \
    gload_lds16(gB0 + ko_, sB + o_ + dst0); \
    gload_lds16(gB1 + ko_, sB + o_ + 4096 + dst0); } while (0)

  STAGE_A(0); STAGE_B(0); STAGE_A(1); STAGE_B(1);
  asm volatile("s_waitcnt vmcnt(4)" ::: "memory");  // tile 0 landed
  __builtin_amdgcn_s_barrier();

  const int NT = D / 32;  // 64
#pragma unroll 1
  for (int t = 0; t < NT; ++t) {
    const unsigned short* pA = sA + (t & 3) * 8192 + aoff;
    const unsigned short* pB = sB + (t & 3) * 8192 + boff;
    // ---- phase 0 issue: 8 ds_read + stage A(t+2) ----
    bf16x8 a0[4], b[4];
#pragma unroll
    for (int i = 0; i < 4; ++i)
      a0[i] = __builtin_bit_cast(bf16x8, *(const u16x8*)(pA + i * 512));
#pragma unroll
    for (int j = 0; j < 4; ++j)
      b[j] = __builtin_bit_cast(bf16x8, *(const u16x8*)(pB + j * 512));
    if (t + 2 < NT) STAGE_A(t + 2);
    __builtin_amdgcn_s_barrier();
    __builtin_amdgcn_s_setprio(1);
#pragma unroll
    for (int i = 0; i < 4; ++i)
#pragma unroll
      for (int j = 0; j < 4; ++j)
        acc[i][j] = __builtin_amdgcn_mfma_f32_16x16x32_bf16(a0[i], b[j], acc[i][j], 0, 0, 0);
    __builtin_amdgcn_s_setprio(0);
    __builtin_amdgcn_s_barrier();
    // ---- phase 1 issue: 4 ds_read + stage B(t+2) (b[] reused) ----
    bf16x8 a1[4];
#pragma unroll
    for (int i = 0; i < 4; ++i)
      a1[i] = __builtin_bit_cast(bf16x8, *(const u16x8*)(pA + (i + 4) * 512));
    if (t + 2 < NT) STAGE_B(t + 2);
    __builtin_amdgcn_s_barrier();
    __builtin_amdgcn_s_setprio(1);
#pragma unroll
    for (int i = 0; i < 4; ++i)
#pragma unroll
      for (int j = 0; j < 4; ++j)
        acc[i + 4][j] = __builtin_amdgcn_mfma_f32_16x16x32_bf16(a1[i], b[j], acc[i + 4][j], 0, 0, 0);
    __builtin_amdgcn_s_setprio(0);
    // guarantee tile t+1 resident before its reads; keep t+2's 4 loads in flight
    if (t < NT - 2) asm volatile("s_waitcnt vmcnt(4)" ::: "memory");
    else            asm volatile("s_waitcnt vmcnt(0)" ::: "memory");
    __builtin_amdgcn_s_barrier();
  }

  // epilogue: dt = h @ W2^T + b2 (rank-64, 2 MFMA per fragment), out = acc*dt + Dp
  bf16x8 wb0[4], wb1[4];
  float b2v[4], dpv[4];
#pragma unroll
  for (int j = 0; j < 4; ++j) {
    int n = n0 + wn * 64 + j * 16 + lm;
    const u16x8* wp = (const u16x8*)(w2bf + (size_t)n * R + lk * 8);
    wb0[j] = __builtin_bit_cast(bf16x8, wp[0]);
    wb1[j] = __builtin_bit_cast(bf16x8, wp[4]);  // +32 bf16
    b2v[j] = b2[n];
    dpv[j] = dp[n];
  }
#pragma unroll
  for (int mi = 0; mi < 8; ++mi) {
    int hrow = m0 + wm * 128 + mi * 16 + lm;
    const u16x8* hp = (const u16x8*)(hbf + (size_t)hrow * R + lk * 8);
    bf16x8 ha0 = __builtin_bit_cast(bf16x8, hp[0]);
    bf16x8 ha1 = __builtin_bit_cast(bf16x8, hp[4]);
    int mbase = m0 + wm * 128 + mi * 16 + lk * 4;
#pragma unroll
    for (int j = 0; j < 4; ++j) {
      f32x4 dt = {};
      dt = __builtin_amdgcn_mfma_f32_16x16x32_bf16(ha0, wb0[j], dt, 0, 0, 0);
      dt = __builtin_amdgcn_mfma_f32_16x16x32_bf16(ha1, wb1[j], dt, 0, 0, 0);
      int n = n0 + wn * 64 + j * 16 + lm;
#pragma unroll
      for (int r = 0; r < 4; ++r) {
        float val = acc[mi][j][r] * (dt[r] + b2v[j]) + dpv[j];
        out[(size_t)(mbase + r) * D + n] = val;
      }
    }
  }
#undef STAGE_A
#undef STAGE_B
}

extern "C" void kernel_launch(void* const* d_in, const int* in_sizes, int n_in,
                              void* d_out, int out_size, void* d_ws, size_t ws_size,
                              hipStream_t stream) {
  const float* x  = (const float*)d_in[0];
  const float* A  = (const float*)d_in[1];
  const float* B  = (const float*)d_in[2];
  const float* C  = (const float*)d_in[3];
  const float* Dp = (const float*)d_in[4];
  const float* W1 = (const float*)d_in[5];
  const float* b1 = (const float*)d_in[6];
  const float* W2 = (const float*)d_in[7];
  const float* b2 = (const float*)d_in[8];
  float* out = (float*)d_out;

  uint8_t* ws = (uint8_t*)d_ws;
  unsigned short* xbf  = (unsigned short*)ws;                                // 32 MB
  unsigned short* st   = (unsigned short*)(ws + (32u << 20));                // 8 MB
  unsigned short* w1bf = (unsigned short*)(ws + (40u << 20));                // 256 KB
  unsigned short* w2bf = (unsigned short*)(ws + (40u << 20) + (256u << 10)); // 256 KB
  unsigned short* hbf  = (unsigned short*)(ws + (41u << 20));                // 1 MB

  conv_kernel<<<2048, 256, 0, stream>>>(x, W1, W2, xbf, w1bf, w2bf);
  sumt_kernel<<<1024, 256, 0, stream>>>(A, B, C, st);
  h_kernel<<<128, 256, 0, stream>>>(xbf, w1bf, b1, hbf);
  gemm_kernel<<<256, 512, 0, stream>>>(xbf, st, hbf, w2bf, b2, Dp, out);
}

// Round 3
// 118.927 us; speedup vs baseline: 1.8257x; 1.1461x over previous
//
#include <hip/hip_runtime.h>
#include <stdint.h>

#define D 2048
#define R 64
#define M_TOTAL 8192

typedef float f32x4 __attribute__((ext_vector_type(4)));
typedef __bf16 bf16x8 __attribute__((ext_vector_type(8)));
typedef unsigned short u16x8 __attribute__((ext_vector_type(8)));
typedef unsigned short u16x4 __attribute__((ext_vector_type(4)));

__device__ __forceinline__ unsigned short f2bf(float f) {
  unsigned u = __builtin_bit_cast(unsigned, f);
  u += 0x7FFFu + ((u >> 16) & 1u);
  return (unsigned short)(u >> 16);
}

__device__ __forceinline__ void gload_lds16(const void* g, void* l) {
  __builtin_amdgcn_global_load_lds(
      (const __attribute__((address_space(1))) void*)g,
      (__attribute__((address_space(3))) void*)l, 16, 0, 0);
}

// ---------------- fused prep: sumt (blocks 0..1023) + conv (blocks 1024..2047) ----
__global__ void prep_kernel(const float* __restrict__ x, const float* __restrict__ A,
                            const float* __restrict__ B, const float* __restrict__ C,
                            const float* __restrict__ w1, const float* __restrict__ w2,
                            unsigned short* __restrict__ xbf, unsigned short* __restrict__ st,
                            unsigned short* __restrict__ w1bf, unsigned short* __restrict__ w2bf) {
  __shared__ unsigned short lds[64][68];
  int t = threadIdx.x;
  if (blockIdx.x < 1024) {
    // St[n][k] = bf16(A[k][n]+B[k][n]+C[k][n])
    int tk = blockIdx.x >> 5, tn = blockIdx.x & 31;
    int k0 = tk * 64, n0 = tn * 64;
#pragma unroll
    for (int q = 0; q < 4; ++q) {
      int row = q * 16 + (t >> 4);
      int col = (t & 15) * 4;
      size_t off = (size_t)(k0 + row) * D + n0 + col;
      float4 a = *(const float4*)(A + off);
      float4 b = *(const float4*)(B + off);
      float4 c = *(const float4*)(C + off);
      u16x4 o = { f2bf(a.x + b.x + c.x), f2bf(a.y + b.y + c.y),
                  f2bf(a.z + b.z + c.z), f2bf(a.w + b.w + c.w) };
      *(u16x4*)(&lds[row][col]) = o;
    }
    __syncthreads();
    int n = t >> 2, kc = (t & 3) * 16;
    u16x8 v0, v1;
#pragma unroll
    for (int jj = 0; jj < 8; ++jj) v0[jj] = lds[kc + jj][n];
#pragma unroll
    for (int jj = 0; jj < 8; ++jj) v1[jj] = lds[kc + 8 + jj][n];
    size_t ooff = (size_t)(n0 + n) * D + k0 + kc;
    *(u16x8*)(st + ooff) = v0;
    *(u16x8*)(st + ooff + 8) = v1;
  } else {
    // f32 -> bf16 conversions (x, W1, W2), grid-stride over 1024 blocks
    const int NX4 = (M_TOTAL * D) / 4;
    const int NW4 = (R * D) / 4;
    int stride = 1024 * 256;
    for (int i = (blockIdx.x - 1024) * 256 + t; i < NX4 + 2 * NW4; i += stride) {
      const float4* src; unsigned short* dst; int j;
      if (i < NX4)            { src = (const float4*)x;  dst = xbf;  j = i; }
      else if (i < NX4 + NW4) { src = (const float4*)w1; dst = w1bf; j = i - NX4; }
      else                    { src = (const float4*)w2; dst = w2bf; j = i - NX4 - NW4; }
      float4 v = src[j];
      u16x4 o = { f2bf(v.x), f2bf(v.y), f2bf(v.z), f2bf(v.w) };
      *(u16x4*)(dst + (size_t)j * 4) = o;
    }
  }
}

// ---------------- h = bf16(gelu(x @ W1^T + b1)), 4-deep ring + counted vmcnt ----
__global__ __launch_bounds__(256) void h_kernel(const unsigned short* __restrict__ xbf,
                                                const unsigned short* __restrict__ w1bf,
                                                const float* __restrict__ b1,
                                                unsigned short* __restrict__ hbf) {
  __shared__ unsigned short sX[4 * 2048];
  __shared__ unsigned short sW[4 * 2048];
  int t = threadIdx.x;
  int w = t >> 6, l = t & 63;
  int lm = l & 15, lk = l >> 4;
  int m0 = blockIdx.x * 64;
  f32x4 acc[4] = {};

  const unsigned short* srcX = xbf + (size_t)(m0 + (t & 63)) * D + (t >> 6) * 8;
  const unsigned short* srcW = w1bf + (size_t)(t & 63) * D + (t >> 6) * 8;
  const int dstw = w * 512;

#define HSTAGE(kt) do { \
    gload_lds16(srcX + (kt) * 32, sX + ((kt) & 3) * 2048 + dstw); \
    gload_lds16(srcW + (kt) * 32, sW + ((kt) & 3) * 2048 + dstw); } while (0)

  HSTAGE(0); HSTAGE(1); HSTAGE(2);
  asm volatile("s_waitcnt vmcnt(4)" ::: "memory");
  __builtin_amdgcn_s_barrier();

#pragma unroll 1
  for (int kt = 0; kt < 64; ++kt) {
    const unsigned short* bX = sX + (kt & 3) * 2048;
    const unsigned short* bW = sW + (kt & 3) * 2048;
    bf16x8 a = __builtin_bit_cast(bf16x8, *(const u16x8*)(bX + lk * 512 + (w * 16 + lm) * 8));
    bf16x8 bw[4];
#pragma unroll
    for (int j = 0; j < 4; ++j)
      bw[j] = __builtin_bit_cast(bf16x8, *(const u16x8*)(bW + lk * 512 + (j * 16 + lm) * 8));
    if (kt + 3 < 64) HSTAGE(kt + 3);
#pragma unroll
    for (int j = 0; j < 4; ++j)
      acc[j] = __builtin_amdgcn_mfma_f32_16x16x32_bf16(a, bw[j], acc[j], 0, 0, 0);
    if (kt < 61) asm volatile("s_waitcnt vmcnt(4)" ::: "memory");
    else         asm volatile("s_waitcnt vmcnt(0)" ::: "memory");
    __builtin_amdgcn_s_barrier();
  }
#undef HSTAGE

  int m_base = m0 + w * 16 + lk * 4;
#pragma unroll
  for (int j = 0; j < 4; ++j) {
    int n = j * 16 + lm;
    float bv = b1[n];
#pragma unroll
    for (int r = 0; r < 4; ++r) {
      float v = acc[j][r] + bv;
      float g = 0.5f * v * (1.0f + erff(v * 0.70710678118654752f));
      hbf[(size_t)(m_base + r) * R + n] = f2bf(g);
    }
  }
}

// ---------------- main: out = (x @ S) * dt + Dp ----------------
// 256x256 tile, BK=64, 8 waves (2M x 4N), m201-style 4-phase schedule:
// per phase {ds_read subtile || stage 1 half-tile -> barrier -> lgkmcnt(0) ->
// setprio(1) -> 16 MFMA (one C-quadrant) -> setprio(0) -> barrier}; one
// counted vmcnt(4) per K-tile. XOR swizzle: phys granule = kgran ^ (row&7).
__global__ __launch_bounds__(512, 2) void gemm_kernel(
    const unsigned short* __restrict__ xbf, const unsigned short* __restrict__ st,
    const unsigned short* __restrict__ hbf, const unsigned short* __restrict__ w2bf,
    const float* __restrict__ b2, const float* __restrict__ dp,
    float* __restrict__ out) {
  __shared__ unsigned short sA[2 * 16384];  // 2 bufs x 256 rows x 64 k, 64 KB
  __shared__ unsigned short sB[2 * 16384];  // 64 KB
  const int tid = threadIdx.x;
  const int w = tid >> 6, l = tid & 63, lk = l >> 4, lm = l & 15;
  const int wm = w >> 2, wn = w & 3;
  int bid = blockIdx.x;
  int wg = (bid & 7) * 32 + (bid >> 3);  // bijective XCD swizzle (256 wgs)
  int mb = wg >> 3, nb = wg & 7;
  int m0 = mb * 256, n0 = nb * 256;

  // staging: chunk p = q*512 + tid; row = p>>3; phys granule gp = p&7;
  // logical granule kg = gp ^ (row&7) -- same value for q=0/1 (row +64).
  const int kg = (tid & 7) ^ ((tid >> 3) & 7);
  const unsigned short* gA = xbf + (size_t)(m0 + (tid >> 3)) * D + kg * 8;
  const unsigned short* gB = st + (size_t)(n0 + (tid >> 3)) * D + kg * 8;
  const int dstw = w * 512;  // shorts; wave-uniform base (HW adds lane*16B)

  // fragment reads: row&7 == lm&7 for all frags
  const int s7 = lm & 7;
  const int gsw0 = (lk ^ s7) * 8;        // kk=0
  const int gsw1 = ((4 | lk) ^ s7) * 8;  // kk=1
  const int arow = (wm * 128 + lm) * 64;
  const int brow = (wn * 64 + lm) * 64;

  f32x4 acc[8][4] = {};

#define STAGE(gptr, sbuf, T, h) do { \
    const unsigned short* g_ = (gptr) + (size_t)((h) * 128) * D + (T) * 64; \
    unsigned short* d_ = (sbuf) + (((T) & 1) * 16384 + (h) * 8192 + dstw); \
    gload_lds16(g_, d_); \
    gload_lds16(g_ + 64 * D, d_ + 4096); } while (0)

#define LD8(buf, off) __builtin_bit_cast(bf16x8, *(const u16x8*)((buf) + (off)))

  // prologue: tile0 all 4 halves + tile1 B halves; drain tile0
  STAGE(gA, sA, 0, 0); STAGE(gA, sA, 0, 1);
  STAGE(gB, sB, 0, 0); STAGE(gB, sB, 0, 1);
  STAGE(gB, sB, 1, 0); STAGE(gB, sB, 1, 1);
  asm volatile("s_waitcnt vmcnt(4)" ::: "memory");
  __builtin_amdgcn_s_barrier();

  const int NT = D / 64;  // 32
#pragma unroll 1
  for (int kt = 0; kt < NT; ++kt) {
    const unsigned short* bufA = sA + (kt & 1) * 16384;
    const unsigned short* bufB = sB + (kt & 1) * 16384;
    bf16x8 a[4][2], b0[2][2], b1[2][2];

    // ---- P0: read A-half(wm) frags 0-3 + B-half(wn) frags 0-1; stage kt+1.A0
    #pragma unroll
    for (int i = 0; i < 4; ++i) {
      a[i][0] = LD8(bufA, arow + i * 1024 + gsw0);
      a[i][1] = LD8(bufA, arow + i * 1024 + gsw1);
    }
    #pragma unroll
    for (int j = 0; j < 2; ++j) {
      b0[j][0] = LD8(bufB, brow + j * 1024 + gsw0);
      b0[j][1] = LD8(bufB, brow + j * 1024 + gsw1);
    }
    if (kt + 1 < NT) STAGE(gA, sA, kt + 1, 0);
    __builtin_amdgcn_s_barrier();
    asm volatile("s_waitcnt lgkmcnt(0)" ::: "memory");
    __builtin_amdgcn_s_setprio(1);
    #pragma unroll
    for (int i = 0; i < 4; ++i)
      #pragma unroll
      for (int j = 0; j < 2; ++j) {
        acc[i][j] = __builtin_amdgcn_mfma_f32_16x16x32_bf16(a[i][0], b0[j][0], acc[i][j], 0, 0, 0);
        acc[i][j] = __builtin_amdgcn_mfma_f32_16x16x32_bf16(a[i][1], b0[j][1], acc[i][j], 0, 0, 0);
      }
    __builtin_amdgcn_s_setprio(0);
    __builtin_amdgcn_s_barrier();

    // ---- P1: read B frags 2-3; stage kt+1.A1; MFMA Q(0,1)
    #pragma unroll
    for (int j = 0; j < 2; ++j) {
      b1[j][0] = LD8(bufB, brow + (j + 2) * 1024 + gsw0);
      b1[j][1] = LD8(bufB, brow + (j + 2) * 1024 + gsw1);
    }
    if (kt + 1 < NT) STAGE(gA, sA, kt + 1, 1);
    __builtin_amdgcn_s_barrier();
    asm volatile("s_waitcnt lgkmcnt(0)" ::: "memory");
    __builtin_amdgcn_s_setprio(1);
    #pragma unroll
    for (int i = 0; i < 4; ++i)
      #pragma unroll
      for (int j = 0; j < 2; ++j) {
        acc[i][j + 2] = __builtin_amdgcn_mfma_f32_16x16x32_bf16(a[i][0], b1[j][0], acc[i][j + 2], 0, 0, 0);
        acc[i][j + 2] = __builtin_amdgcn_mfma_f32_16x16x32_bf16(a[i][1], b1[j][1], acc[i][j + 2], 0, 0, 0);
      }
    __builtin_amdgcn_s_setprio(0);
    __builtin_amdgcn_s_barrier();

    // ---- P2: read A frags 4-7 (reuse regs); stage kt+2.B0; MFMA Q(1,1)
    #pragma unroll
    for (int i = 0; i < 4; ++i) {
      a[i][0] = LD8(bufA, arow + (i + 4) * 1024 + gsw0);
      a[i][1] = LD8(bufA, arow + (i + 4) * 1024 + gsw1);
    }
    if (kt + 2 < NT) STAGE(gB, sB, kt + 2, 0);
    __builtin_amdgcn_s_barrier();
    asm volatile("s_waitcnt lgkmcnt(0)" ::: "memory");
    __builtin_amdgcn_s_setprio(1);
    #pragma unroll
    for (int i = 0; i < 4; ++i)
      #pragma unroll
      for (int j = 0; j < 2; ++j) {
        acc[i + 4][j + 2] = __builtin_amdgcn_mfma_f32_16x16x32_bf16(a[i][0], b1[j][0], acc[i + 4][j + 2], 0, 0, 0);
        acc[i + 4][j + 2] = __builtin_amdgcn_mfma_f32_16x16x32_bf16(a[i][1], b1[j][1], acc[i + 4][j + 2], 0, 0, 0);
      }
    __builtin_amdgcn_s_setprio(0);
    __builtin_amdgcn_s_barrier();

    // ---- P3: no reads; stage kt+2.B1; MFMA Q(1,0); counted drain of kt+1
    if (kt + 2 < NT) STAGE(gB, sB, kt + 2, 1);
    __builtin_amdgcn_s_setprio(1);
    #pragma unroll
    for (int i = 0; i < 4; ++i)
      #pragma unroll
      for (int j = 0; j < 2; ++j) {
        acc[i + 4][j] = __builtin_amdgcn_mfma_f32_16x16x32_bf16(a[i][0], b0[j][0], acc[i + 4][j], 0, 0, 0);
        acc[i + 4][j] = __builtin_amdgcn_mfma_f32_16x16x32_bf16(a[i][1], b0[j][1], acc[i + 4][j], 0, 0, 0);
      }
    __builtin_amdgcn_s_setprio(0);
    if (kt < NT - 2) asm volatile("s_waitcnt vmcnt(4)" ::: "memory");
    else             asm volatile("s_waitcnt vmcnt(0)" ::: "memory");
    __builtin_amdgcn_s_barrier();
  }

  // epilogue: dt = h @ W2^T + b2 (rank-64), out = acc*dt + Dp
  bf16x8 wb0[4], wb1[4];
  float b2v[4], dpv[4];
#pragma unroll
  for (int j = 0; j < 4; ++j) {
    int n = n0 + wn * 64 + j * 16 + lm;
    const u16x8* wp = (const u16x8*)(w2bf + (size_t)n * R + lk * 8);
    wb0[j] = __builtin_bit_cast(bf16x8, wp[0]);
    wb1[j] = __builtin_bit_cast(bf16x8, wp[4]);  // +32 bf16
    b2v[j] = b2[n];
    dpv[j] = dp[n];
  }
#pragma unroll
  for (int mi = 0; mi < 8; ++mi) {
    int hrow = m0 + wm * 128 + mi * 16 + lm;
    const u16x8* hp = (const u16x8*)(hbf + (size_t)hrow * R + lk * 8);
    bf16x8 ha0 = __builtin_bit_cast(bf16x8, hp[0]);
    bf16x8 ha1 = __builtin_bit_cast(bf16x8, hp[4]);
    int mbase = m0 + wm * 128 + mi * 16 + lk * 4;
#pragma unroll
    for (int j = 0; j < 4; ++j) {
      f32x4 dt = {};
      dt = __builtin_amdgcn_mfma_f32_16x16x32_bf16(ha0, wb0[j], dt, 0, 0, 0);
      dt = __builtin_amdgcn_mfma_f32_16x16x32_bf16(ha1, wb1[j], dt, 0, 0, 0);
      int n = n0 + wn * 64 + j * 16 + lm;
#pragma unroll
      for (int r = 0; r < 4; ++r) {
        float val = acc[mi][j][r] * (dt[r] + b2v[j]) + dpv[j];
        out[(size_t)(mbase + r) * D + n] = val;
      }
    }
  }
#undef STAGE
#undef LD8
}

extern "C" void kernel_launch(void* const* d_in, const int* in_sizes, int n_in,
                              void* d_out, int out_size, void* d_ws, size_t ws_size,
                              hipStream_t stream) {
  const float* x  = (const float*)d_in[0];
  const float* A  = (const float*)d_in[1];
  const float* B  = (const float*)d_in[2];
  const float* C  = (const float*)d_in[3];
  const float* Dp = (const float*)d_in[4];
  const float* W1 = (const float*)d_in[5];
  const float* b1 = (const float*)d_in[6];
  const float* W2 = (const float*)d_in[7];
  const float* b2 = (const float*)d_in[8];
  float* out = (float*)d_out;

  uint8_t* ws = (uint8_t*)d_ws;
  unsigned short* xbf  = (unsigned short*)ws;                                // 32 MB
  unsigned short* st   = (unsigned short*)(ws + (32u << 20));                // 8 MB
  unsigned short* w1bf = (unsigned short*)(ws + (40u << 20));                // 256 KB
  unsigned short* w2bf = (unsigned short*)(ws + (40u << 20) + (256u << 10)); // 256 KB
  unsigned short* hbf  = (unsigned short*)(ws + (41u << 20));                // 1 MB

  prep_kernel<<<2048, 256, 0, stream>>>(x, A, B, C, W1, W2, xbf, st, w1bf, w2bf);
  h_kernel<<<128, 256, 0, stream>>>(xbf, w1bf, b1, hbf);
  gemm_kernel<<<256, 512, 0, stream>>>(xbf, st, hbf, w2bf, b2, Dp, out);
}